// Round 8
// baseline (15.097 us; speedup 1.0000x reference)
//
#include <hip/hip_runtime.h>
#include <math.h>

#define BATCH 1024
#define SEQ   200
#define DIM   128
#define NT    512

__global__ __launch_bounds__(NT, 8) void dft_layer_kernel(
    const int* __restrict__ seqs,
    const float* __restrict__ emb,
    float* __restrict__ out)
{
    const int b   = blockIdx.x;
    const int tid = threadIdx.x;
    const int c4  = tid & 31;   // float4 chunk within the 128-float row
    const int g   = tid >> 5;   // s-group 0..15

    __shared__ int   s_seq[SEQ];
    __shared__ float s_mag[SEQ];
    __shared__ int   s_match[SEQ];
    __shared__ int   s_cnt[3];         // [0]=L, [1]=M, [2]=max nonzero pos
    __shared__ float s_sum;
    __shared__ float s_part[16][DIM];  // 16 s-groups x 128 floats (8 KB)

    const float4* ebase = (const float4*)(emb + (size_t)b * SEQ * DIM);

    if (tid < 3)  s_cnt[tid] = 0;
    if (tid == 0) s_sum = 0.0f;

    // issue seq load, then speculative gather loads for rows 1..48 (always
    // in-bounds of the 200-row slab; masked by s<L later). These stay in
    // flight through the preamble, hiding its dependent-latency chain.
    int tok = 0;
    if (tid < SEQ) tok = seqs[b * SEQ + tid];
    const int sp0 = 1 + g, sp1 = 17 + g, sp2 = 33 + g;
    float4 p0 = ebase[sp0 * 32 + c4];
    float4 p1 = ebase[sp1 * 32 + c4];
    float4 p2 = ebase[sp2 * 32 + c4];

    if (tid < SEQ) s_seq[tid] = tok;

    // epoch 1: L (count of nonzeros) AND position of last nonzero, together
    unsigned long long bal = __ballot((tid < SEQ) && (tok != 0));
    if (((tid & 63) == 0) && bal) {
        atomicAdd(&s_cnt[0], __popcll(bal));
        int wmax = (tid & ~63) + (63 - (int)__clzll(bal));
        atomicMax(&s_cnt[2], wmax);
    }
    __syncthreads();
    const int L    = s_cnt[0];
    const int last = s_seq[s_cnt[2]];   // == s_seq[L-1]

    // epoch 2: positions where token == last; M==1 for ~99.9% of rows
    if ((tid < L) && (tok == last)) {
        int idx = atomicAdd(&s_cnt[1], 1);
        s_match[idx] = tid;
    }
    __syncthreads();
    const int M = s_cnt[1];

    float invSum;
    if (M == 1) {
        // single impulse at n=L-1 -> |DFT_k| == 1 for all k -> uniform weights
        invSum = 1.0f / (float)(L - 1);
    } else {
        // rare path: explicit DFT magnitude over the M impulses
        const float Lf = (float)L;
        float mag = 0.0f;
        if (tid < L - 1) {
            float re = 0.0f, im = 0.0f;
            const float kf = (float)tid;
            for (int m = 0; m < M; ++m) {
                float rev = kf * (float)s_match[m] / Lf;  // theta in revolutions
                rev -= floorf(rev);                        // sign dropped: |.| is even
                float th = 6.2831855f * rev;
                re += __cosf(th);
                im += __sinf(th);
            }
            mag = sqrtf(re * re + im * im);
        }
        if (tid < SEQ) s_mag[tid] = mag;
        float v = mag;
        #pragma unroll
        for (int o = 32; o > 0; o >>= 1) v += __shfl_down(v, o, 64);
        if ((tid & 63) == 0) atomicAdd(&s_sum, v);
        __syncthreads();                    // block-uniform branch: legal
        invSum = 1.0f / s_sum;
    }

    // gather: out[b,:] = invSum * sum_{s=1}^{L-1} w[s-1] * emb[b,s,:]
    float4 a0 = make_float4(0.f, 0.f, 0.f, 0.f);
    float4 a1 = make_float4(0.f, 0.f, 0.f, 0.f);

    if (M == 1) {
        float w0 = (sp0 < L) ? 1.0f : 0.0f;
        float w1 = (sp1 < L) ? 1.0f : 0.0f;
        float w2 = (sp2 < L) ? 1.0f : 0.0f;
        a0.x = w0 * p0.x + w2 * p2.x; a0.y = w0 * p0.y + w2 * p2.y;
        a0.z = w0 * p0.z + w2 * p2.z; a0.w = w0 * p0.w + w2 * p2.w;
        a1.x = w1 * p1.x; a1.y = w1 * p1.y; a1.z = w1 * p1.z; a1.w = w1 * p1.w;
        int s = 49 + g;
        for (; s + 48 < L; s += 64) {   // unroll-4: 4 loads in flight
            float4 e0 = ebase[(s     ) * 32 + c4];
            float4 e1 = ebase[(s + 16) * 32 + c4];
            float4 e2 = ebase[(s + 32) * 32 + c4];
            float4 e3 = ebase[(s + 48) * 32 + c4];
            a0.x += e0.x; a0.y += e0.y; a0.z += e0.z; a0.w += e0.w;
            a1.x += e1.x; a1.y += e1.y; a1.z += e1.z; a1.w += e1.w;
            a0.x += e2.x; a0.y += e2.y; a0.z += e2.z; a0.w += e2.w;
            a1.x += e3.x; a1.y += e3.y; a1.z += e3.z; a1.w += e3.w;
        }
        for (; s + 16 < L; s += 32) {   // unroll-2 tail
            float4 e0 = ebase[(s     ) * 32 + c4];
            float4 e1 = ebase[(s + 16) * 32 + c4];
            a0.x += e0.x; a0.y += e0.y; a0.z += e0.z; a0.w += e0.w;
            a1.x += e1.x; a1.y += e1.y; a1.z += e1.z; a1.w += e1.w;
        }
        if (s < L) {
            float4 e0 = ebase[s * 32 + c4];
            a0.x += e0.x; a0.y += e0.y; a0.z += e0.z; a0.w += e0.w;
        }
    } else {
        float w0 = (sp0 < L) ? s_mag[sp0 - 1] : 0.0f;
        float w1 = (sp1 < L) ? s_mag[sp1 - 1] : 0.0f;
        float w2 = (sp2 < L) ? s_mag[sp2 - 1] : 0.0f;
        a0.x = w0 * p0.x + w2 * p2.x; a0.y = w0 * p0.y + w2 * p2.y;
        a0.z = w0 * p0.z + w2 * p2.z; a0.w = w0 * p0.w + w2 * p2.w;
        a1.x = w1 * p1.x; a1.y = w1 * p1.y; a1.z = w1 * p1.z; a1.w = w1 * p1.w;
        int s = 49 + g;
        for (; s + 48 < L; s += 64) {
            float u0 = s_mag[s - 1],  u1 = s_mag[s + 15];
            float u2 = s_mag[s + 31], u3 = s_mag[s + 47];
            float4 e0 = ebase[(s     ) * 32 + c4];
            float4 e1 = ebase[(s + 16) * 32 + c4];
            float4 e2 = ebase[(s + 32) * 32 + c4];
            float4 e3 = ebase[(s + 48) * 32 + c4];
            a0.x += u0 * e0.x; a0.y += u0 * e0.y; a0.z += u0 * e0.z; a0.w += u0 * e0.w;
            a1.x += u1 * e1.x; a1.y += u1 * e1.y; a1.z += u1 * e1.z; a1.w += u1 * e1.w;
            a0.x += u2 * e2.x; a0.y += u2 * e2.y; a0.z += u2 * e2.z; a0.w += u2 * e2.w;
            a1.x += u3 * e3.x; a1.y += u3 * e3.y; a1.z += u3 * e3.z; a1.w += u3 * e3.w;
        }
        for (; s + 16 < L; s += 32) {
            float u0 = s_mag[s - 1], u1 = s_mag[s + 15];
            float4 e0 = ebase[(s     ) * 32 + c4];
            float4 e1 = ebase[(s + 16) * 32 + c4];
            a0.x += u0 * e0.x; a0.y += u0 * e0.y; a0.z += u0 * e0.z; a0.w += u0 * e0.w;
            a1.x += u1 * e1.x; a1.y += u1 * e1.y; a1.z += u1 * e1.z; a1.w += u1 * e1.w;
        }
        if (s < L) {
            float u0 = s_mag[s - 1];
            float4 e0 = ebase[s * 32 + c4];
            a0.x += u0 * e0.x; a0.y += u0 * e0.y; a0.z += u0 * e0.z; a0.w += u0 * e0.w;
        }
    }

    a0.x += a1.x; a0.y += a1.y; a0.z += a1.z; a0.w += a1.w;
    {
        float* p = &s_part[g][c4 << 2];
        p[0] = a0.x; p[1] = a0.y; p[2] = a0.z; p[3] = a0.w;
    }
    __syncthreads();
    if (tid < DIM) {
        float r = 0.0f;
        #pragma unroll
        for (int gg = 0; gg < 16; ++gg) r += s_part[gg][tid];
        out[(size_t)b * DIM + tid] = r * invSum;
    }
}

extern "C" void kernel_launch(void* const* d_in, const int* in_sizes, int n_in,
                              void* d_out, int out_size, void* d_ws, size_t ws_size,
                              hipStream_t stream) {
    const int*   seqs = (const int*)d_in[0];
    const float* emb  = (const float*)d_in[1];
    float*       out  = (float*)d_out;
    dft_layer_kernel<<<BATCH, NT, 0, stream>>>(seqs, emb, out);
}

// Round 9
// 14.974 us; speedup vs baseline: 1.0082x; 1.0082x over previous
//
#include <hip/hip_runtime.h>
#include <math.h>

#define BATCH 1024
#define SEQ   200
#define DIM   128
#define NT    512

__global__ __launch_bounds__(NT, 8) void dft_layer_kernel(
    const int* __restrict__ seqs,
    const float* __restrict__ emb,
    float* __restrict__ out)
{
    const int b    = blockIdx.x;
    const int tid  = threadIdx.x;
    const int lane = tid & 63;
    const int c4   = tid & 31;   // float4 chunk within the 128-float row
    const int g    = tid >> 5;   // s-group 0..15

    __shared__ float s_mag[SEQ];
    __shared__ int   s_match[SEQ];
    __shared__ int   s_cnt1;
    __shared__ float s_sum;
    __shared__ float s_part[16][DIM];  // 16 s-groups x 128 floats (8 KB)

    const float4* ebase = (const float4*)(emb + (size_t)b * SEQ * DIM);

    // Every wave loads the whole token row: one int4 per lane (50 lanes cover
    // 200 tokens). Redundant across waves but L1-cached; buys a barrier-free
    // preamble (each wave derives L/last/M in registers independently).
    int4 t4 = make_int4(0, 0, 0, 0);
    if (lane < SEQ / 4) t4 = ((const int4*)(seqs + (size_t)b * SEQ))[lane];

    // speculative gather loads for rows 1..32 (always in-bounds; masked by
    // s<L later) -- in flight through the whole preamble.
    const int sp0 = 1 + g, sp1 = 17 + g;
    float4 p0 = ebase[sp0 * 32 + c4];
    float4 p1 = ebase[sp1 * 32 + c4];

    // L = count of nonzero tokens (contiguous at front), butterfly reduce
    int c = (t4.x != 0) + (t4.y != 0) + (t4.z != 0) + (t4.w != 0);
    #pragma unroll
    for (int o = 32; o > 0; o >>= 1) c += __shfl_xor(c, o, 64);
    const int L = c;

    // last real token = token at position L-1 (uniform component select + shfl)
    const int lpos = L - 1;
    int vsel = (lpos & 2) ? ((lpos & 1) ? t4.w : t4.z)
                          : ((lpos & 1) ? t4.y : t4.x);
    const int last = __shfl(vsel, lpos >> 2, 64);

    // M = multiplicity of `last` (padding zeros can't match: last != 0)
    int m = (t4.x == last) + (t4.y == last) + (t4.z == last) + (t4.w == last);
    #pragma unroll
    for (int o = 32; o > 0; o >>= 1) m += __shfl_xor(m, o, 64);
    const int M = m;   // block-uniform (all waves see identical row data)

    float invSum;
    if (M == 1) {
        // single impulse at n=L-1 -> |DFT_k| == 1 for all k -> uniform weights
        invSum = 1.0f / (float)(L - 1);
    } else {
        // rare path (~1 row/batch): explicit DFT magnitude over the M impulses
        if (tid == 0) { s_cnt1 = 0; s_sum = 0.0f; }
        __syncthreads();
        if (tid < SEQ / 4) {   // wave 0 emits match positions from registers
            if (t4.x == last) { int i = atomicAdd(&s_cnt1, 1); s_match[i] = 4*tid;     }
            if (t4.y == last) { int i = atomicAdd(&s_cnt1, 1); s_match[i] = 4*tid + 1; }
            if (t4.z == last) { int i = atomicAdd(&s_cnt1, 1); s_match[i] = 4*tid + 2; }
            if (t4.w == last) { int i = atomicAdd(&s_cnt1, 1); s_match[i] = 4*tid + 3; }
        }
        __syncthreads();
        const float Lf = (float)L;
        float mag = 0.0f;
        if (tid < L - 1) {
            float re = 0.0f, im = 0.0f;
            const float kf = (float)tid;
            for (int mm = 0; mm < M; ++mm) {
                float rev = kf * (float)s_match[mm] / Lf;  // theta in revolutions
                rev -= floorf(rev);                        // sign dropped: |.| even
                float th = 6.2831855f * rev;
                re += __cosf(th);
                im += __sinf(th);
            }
            mag = sqrtf(re * re + im * im);
        }
        if (tid < SEQ) s_mag[tid] = mag;
        float v = mag;
        #pragma unroll
        for (int o = 32; o > 0; o >>= 1) v += __shfl_down(v, o, 64);
        if ((tid & 63) == 0) atomicAdd(&s_sum, v);
        __syncthreads();                    // block-uniform branch: legal
        invSum = 1.0f / s_sum;
    }

    // gather: out[b,:] = invSum * sum_{s=1}^{L-1} w[s-1] * emb[b,s,:]
    float4 a0 = make_float4(0.f, 0.f, 0.f, 0.f);
    float4 a1 = make_float4(0.f, 0.f, 0.f, 0.f);

    if (M == 1) {
        float w0 = (sp0 < L) ? 1.0f : 0.0f;
        float w1 = (sp1 < L) ? 1.0f : 0.0f;
        a0.x = w0 * p0.x; a0.y = w0 * p0.y; a0.z = w0 * p0.z; a0.w = w0 * p0.w;
        a1.x = w1 * p1.x; a1.y = w1 * p1.y; a1.z = w1 * p1.z; a1.w = w1 * p1.w;
        int s = 33 + g;
        for (; s + 48 < L; s += 64) {   // unroll-4: 4 loads in flight
            float4 e0 = ebase[(s     ) * 32 + c4];
            float4 e1 = ebase[(s + 16) * 32 + c4];
            float4 e2 = ebase[(s + 32) * 32 + c4];
            float4 e3 = ebase[(s + 48) * 32 + c4];
            a0.x += e0.x; a0.y += e0.y; a0.z += e0.z; a0.w += e0.w;
            a1.x += e1.x; a1.y += e1.y; a1.z += e1.z; a1.w += e1.w;
            a0.x += e2.x; a0.y += e2.y; a0.z += e2.z; a0.w += e2.w;
            a1.x += e3.x; a1.y += e3.y; a1.z += e3.z; a1.w += e3.w;
        }
        for (; s + 16 < L; s += 32) {   // unroll-2 tail
            float4 e0 = ebase[(s     ) * 32 + c4];
            float4 e1 = ebase[(s + 16) * 32 + c4];
            a0.x += e0.x; a0.y += e0.y; a0.z += e0.z; a0.w += e0.w;
            a1.x += e1.x; a1.y += e1.y; a1.z += e1.z; a1.w += e1.w;
        }
        if (s < L) {
            float4 e0 = ebase[s * 32 + c4];
            a0.x += e0.x; a0.y += e0.y; a0.z += e0.z; a0.w += e0.w;
        }
    } else {
        float w0 = (sp0 < L) ? s_mag[sp0 - 1] : 0.0f;
        float w1 = (sp1 < L) ? s_mag[sp1 - 1] : 0.0f;
        a0.x = w0 * p0.x; a0.y = w0 * p0.y; a0.z = w0 * p0.z; a0.w = w0 * p0.w;
        a1.x = w1 * p1.x; a1.y = w1 * p1.y; a1.z = w1 * p1.z; a1.w = w1 * p1.w;
        int s = 33 + g;
        for (; s + 48 < L; s += 64) {
            float u0 = s_mag[s - 1],  u1 = s_mag[s + 15];
            float u2 = s_mag[s + 31], u3 = s_mag[s + 47];
            float4 e0 = ebase[(s     ) * 32 + c4];
            float4 e1 = ebase[(s + 16) * 32 + c4];
            float4 e2 = ebase[(s + 32) * 32 + c4];
            float4 e3 = ebase[(s + 48) * 32 + c4];
            a0.x += u0 * e0.x; a0.y += u0 * e0.y; a0.z += u0 * e0.z; a0.w += u0 * e0.w;
            a1.x += u1 * e1.x; a1.y += u1 * e1.y; a1.z += u1 * e1.z; a1.w += u1 * e1.w;
            a0.x += u2 * e2.x; a0.y += u2 * e2.y; a0.z += u2 * e2.z; a0.w += u2 * e2.w;
            a1.x += u3 * e3.x; a1.y += u3 * e3.y; a1.z += u3 * e3.z; a1.w += u3 * e3.w;
        }
        for (; s + 16 < L; s += 32) {
            float u0 = s_mag[s - 1], u1 = s_mag[s + 15];
            float4 e0 = ebase[(s     ) * 32 + c4];
            float4 e1 = ebase[(s + 16) * 32 + c4];
            a0.x += u0 * e0.x; a0.y += u0 * e0.y; a0.z += u0 * e0.z; a0.w += u0 * e0.w;
            a1.x += u1 * e1.x; a1.y += u1 * e1.y; a1.z += u1 * e1.z; a1.w += u1 * e1.w;
        }
        if (s < L) {
            float u0 = s_mag[s - 1];
            float4 e0 = ebase[s * 32 + c4];
            a0.x += u0 * e0.x; a0.y += u0 * e0.y; a0.z += u0 * e0.z; a0.w += u0 * e0.w;
        }
    }

    a0.x += a1.x; a0.y += a1.y; a0.z += a1.z; a0.w += a1.w;
    {
        float* p = &s_part[g][c4 << 2];
        p[0] = a0.x; p[1] = a0.y; p[2] = a0.z; p[3] = a0.w;
    }
    __syncthreads();
    if (tid < DIM) {
        float r = 0.0f;
        #pragma unroll
        for (int gg = 0; gg < 16; ++gg) r += s_part[gg][tid];
        out[(size_t)b * DIM + tid] = r * invSum;
    }
}

extern "C" void kernel_launch(void* const* d_in, const int* in_sizes, int n_in,
                              void* d_out, int out_size, void* d_ws, size_t ws_size,
                              hipStream_t stream) {
    const int*   seqs = (const int*)d_in[0];
    const float* emb  = (const float*)d_in[1];
    float*       out  = (float*)d_out;
    dft_layer_kernel<<<BATCH, NT, 0, stream>>>(seqs, emb, out);
}